// Round 2
// baseline (454.780 us; speedup 1.0000x reference)
//
#include <hip/hip_runtime.h>

#define N_U 8192
#define N_V 8192
#define DIM 64
#define NR 5
#define BM 256           // rows per block
#define NSTEP 16         // K-steps per block (K-chunk = 16*32 = 512)
#define KS 32            // K per step

typedef __attribute__((ext_vector_type(8))) short short8;
typedef __attribute__((ext_vector_type(4))) float f32x4;

__device__ inline unsigned short f2bf(float x) {
    unsigned u = __float_as_uint(x);
    return (unsigned short)((u + 0x7FFFu + ((u >> 16) & 1u)) >> 16);
}

__device__ __forceinline__ void gload_lds16(const void* g, void* l) {
    __builtin_amdgcn_global_load_lds(
        (const __attribute__((address_space(1))) void*)g,
        (__attribute__((address_space(3))) void*)l, 16, 0, 0);
}

// P fragment linear index (shorts) for (r, k, o):
//   lane = ((k>>2)&3)*16 + (o&15); j = ((k>>4)&1)*4 + (k&3); ktile = k>>5; n = o>>4
__device__ inline size_t pfrag_idx(int r, int k, int o) {
    int ktile = k >> 5;
    int lane  = ((k >> 2) & 3) * 16 + (o & 15);
    int j     = ((k >> 4) & 1) * 4 + (k & 3);
    int n     = o >> 4;
    return ((((size_t)r * (N_V / 32) + ktile) * 4 + n) * 64 + lane) * 8 + j;
}

// ---------------- P precompute: P[r][v][o] = sum_f feat[v][f] * W[r][f][o] ----
__global__ __launch_bounds__(256) void precompute_P(
    const float* __restrict__ u_feat, const float* __restrict__ v_feat,
    const float* __restrict__ w_u, const float* __restrict__ w_v,
    unsigned short* __restrict__ p_u, unsigned short* __restrict__ p_v)
{
    int wid  = (blockIdx.x * blockDim.x + threadIdx.x) >> 6;
    int lane = threadIdx.x & 63;
    const int tasks = 2 * NR * (N_V / 32);
    if (wid >= tasks) return;
    int dir  = wid / (NR * (N_V / 32));
    int rem  = wid % (NR * (N_V / 32));
    int r    = rem / (N_V / 32);
    int v0   = (rem % (N_V / 32)) * 32;

    const float* feat = dir ? u_feat : v_feat;
    const float* w    = dir ? w_v : w_u;
    unsigned short* dst = dir ? p_v : p_u;

    float wreg[DIM];
#pragma unroll
    for (int f = 0; f < DIM; ++f) wreg[f] = w[(r * DIM + f) * DIM + lane];

    for (int v = v0; v < v0 + 32; ++v) {
        float x = feat[(size_t)v * DIM + lane];
        float acc = 0.f;
#pragma unroll
        for (int f = 0; f < DIM; ++f) acc += __shfl(x, f) * wreg[f];
        dst[pfrag_idx(r, v, lane)] = f2bf(acc);
    }
}

// ---------------- masked GEMM, pipelined ----------------
// out[row][o] += sum_r sum_k mask_r[row][k] * P[r][k][o]
// TRANS=0: row=u, k=v. TRANS=1: row=v, k=u (4x4 reg transpose at staging).
// 512 thr = 8 waves; BM=256 rows; K-chunk 512 (16 steps of 32), grid (32,16).
// Double-buffered LDS: adj tile (swizzled [256][40]) + B fragments (via
// global_load_lds). Prefetch next step before computing current; 1 barrier/step.
template <int TRANS>
__global__ __launch_bounds__(512, 4) void gemm_masked(
    const int* __restrict__ adj, const unsigned short* __restrict__ pfrag,
    float* __restrict__ outp, unsigned int* __restrict__ deg)
{
    __shared__ unsigned char  bufA[2][BM][40];          // 20480 B
    __shared__ unsigned short bufB[2][NR][4][64][8];    // 40960 B

    const int tid  = threadIdx.x;
    const int lane = tid & 63;
    const int wv   = tid >> 6;
    const int b0   = blockIdx.x * BM;
    const int kt0  = blockIdx.y * NSTEP;   // ktile base

    f32x4 acc[2][4];
#pragma unroll
    for (int m = 0; m < 2; ++m)
#pragma unroll
        for (int n = 0; n < 4; ++n) acc[m][n] = (f32x4){0.f, 0.f, 0.f, 0.f};

    unsigned cnt_pack = 0;     // 4 packed byte-counters (per-thread row slots)
    int4 pre[4];

    // --- helpers (macros via lambdas) ---
    auto issueB = [&](int s) {
        const int p = s & 1;
        const int kt = kt0 + s;
        for (int c = wv; c < 20; c += 8) {           // wave-uniform chunks
            int rr = c >> 2, n = c & 3;
            const unsigned short* src =
                pfrag + ((((size_t)rr * (N_V / 32) + kt) * 4 + n) << 9) + lane * 8;
            gload_lds16(src, (void*)&bufB[p][rr][n][0][0]);
        }
    };
    auto loadAdj = [&](int s) {
        const int kbase = (kt0 + s) * KS;
        if (TRANS == 0) {
#pragma unroll
            for (int it = 0; it < 4; ++it) {
                int idx4 = it * 512 + tid;
                int row  = idx4 >> 3;
                int c4   = (idx4 & 7) * 4;
                pre[it] = *(const int4*)(adj + (size_t)(b0 + row) * N_V + (kbase + c4));
            }
        } else {
            int u4 = (tid >> 6) * 4;
            int v4 = (tid & 63) * 4;
#pragma unroll
            for (int c = 0; c < 4; ++c)
                pre[c] = *(const int4*)(adj + (size_t)(kbase + u4 + c) * N_V + (b0 + v4));
        }
    };
    auto packWrite = [&](int s) {
        const int p = s & 1;
        if (TRANS == 0) {
#pragma unroll
            for (int it = 0; it < 4; ++it) {
                int idx4 = it * 512 + tid;
                int row  = idx4 >> 3;
                int c4   = (idx4 & 7) * 4;
                int4 a = pre[it];
                unsigned pk = (a.x & 0xFF) | ((a.y & 0xFF) << 8) |
                              ((a.z & 0xFF) << 16) | ((a.w & 0xFF) << 24);
                int w = ((c4 >> 2) + (row >> 4)) & 7;
                *(unsigned*)&bufA[p][row][w * 4] = pk;
                unsigned c = (a.x != 0) + (a.y != 0) + (a.z != 0) + (a.w != 0);
                cnt_pack += c << (8 * it);
            }
        } else {
            int u4 = (tid >> 6) * 4;
            int v4 = (tid & 63) * 4;
            const int* q0 = (const int*)&pre[0];
            const int* q1 = (const int*)&pre[1];
            const int* q2 = (const int*)&pre[2];
            const int* q3 = (const int*)&pre[3];
#pragma unroll
            for (int cc = 0; cc < 4; ++cc) {
                int x0 = q0[cc], x1 = q1[cc], x2 = q2[cc], x3 = q3[cc];
                unsigned pk = (x0 & 0xFF) | ((x1 & 0xFF) << 8) |
                              ((x2 & 0xFF) << 16) | ((x3 & 0xFF) << 24);
                int row = v4 + cc;
                int w = ((u4 >> 2) + (row >> 4)) & 7;
                *(unsigned*)&bufA[p][row][w * 4] = pk;
                unsigned c = (x0 != 0) + (x1 != 0) + (x2 != 0) + (x3 != 0);
                cnt_pack += c << (8 * cc);
            }
        }
    };
    auto compute = [&](int s) {
        const int p = s & 1;
        unsigned d[2][2];
#pragma unroll
        for (int m = 0; m < 2; ++m) {
            int row = wv * 32 + m * 16 + (lane & 15);
            int sw  = (row >> 4) & 7;
            int lg  = lane >> 4;
            d[m][0] = *(const unsigned*)&bufA[p][row][4 * ((lg + sw) & 7)];
            d[m][1] = *(const unsigned*)&bufA[p][row][4 * ((lg + 4 + sw) & 7)];
        }
        unsigned bx[2][8];
#pragma unroll
        for (int m = 0; m < 2; ++m)
#pragma unroll
            for (int j = 0; j < 4; ++j) {
                bx[m][j]     = (d[m][0] >> (8 * j)) & 0xFFu;
                bx[m][4 + j] = (d[m][1] >> (8 * j)) & 0xFFu;
            }
#pragma unroll
        for (int rr = 0; rr < NR; ++rr) {
            short8 am[2];
#pragma unroll
            for (int m = 0; m < 2; ++m)
#pragma unroll
                for (int j = 0; j < 8; ++j)
                    am[m][j] = (short)(bx[m][j] == (unsigned)(rr + 1) ? 0x3F80 : 0);
#pragma unroll
            for (int n = 0; n < 4; ++n) {
                short8 bf = *(const short8*)&bufB[p][rr][n][lane][0];
                acc[0][n] = __builtin_amdgcn_mfma_f32_16x16x32_bf16(am[0], bf, acc[0][n], 0, 0, 0);
                acc[1][n] = __builtin_amdgcn_mfma_f32_16x16x32_bf16(am[1], bf, acc[1][n], 0, 0, 0);
            }
        }
    };

    // --- prologue: stage step 0 ---
    issueB(0);
    loadAdj(0);
    packWrite(0);
    __syncthreads();

    // --- main pipelined loop ---
    for (int s = 0; s < NSTEP; ++s) {
        if (s + 1 < NSTEP) { issueB(s + 1); loadAdj(s + 1); }
        compute(s);
        if (s + 1 < NSTEP) packWrite(s + 1);
        __syncthreads();
    }

    // --- epilogue: atomic partial accumulate. C: col=lane&15, row=(lane>>4)*4+q ---
#pragma unroll
    for (int m = 0; m < 2; ++m) {
        int rbase = b0 + wv * 32 + m * 16 + ((lane >> 4) << 2);
#pragma unroll
        for (int n = 0; n < 4; ++n)
#pragma unroll
            for (int q = 0; q < 4; ++q)
                atomicAdd(&outp[(size_t)(rbase + q) * DIM + n * 16 + (lane & 15)], acc[m][n][q]);
    }

    // --- degree reduction (reuse bufA as scratch) ---
    __syncthreads();
    unsigned* sc = (unsigned*)&bufA[0][0][0];
    sc[tid] = cnt_pack;
    __syncthreads();
    if (tid < BM) {
        unsigned tot = 0;
        if (TRANS == 0) {
            int it = tid >> 6, srow = tid & 63;
#pragma unroll
            for (int j = 0; j < 8; ++j) tot += (sc[srow * 8 + j] >> (8 * it)) & 0xFFu;
        } else {
            int sv = tid >> 2, cc = tid & 3;
#pragma unroll
            for (int j = 0; j < 8; ++j) tot += (sc[sv + 64 * j] >> (8 * cc)) & 0xFFu;
        }
        atomicAdd(&deg[b0 + tid], tot);
    }
}

// ---------------- finalize: scale by 1/deg, ReLU ----------------
__global__ __launch_bounds__(256) void finalize_k(
    float* __restrict__ outp, const unsigned int* __restrict__ deg_u,
    const unsigned int* __restrict__ deg_v)
{
    int idx = blockIdx.x * blockDim.x + threadIdx.x;
    const int total = 2 * N_U * DIM;
    for (; idx < total; idx += gridDim.x * blockDim.x) {
        int row = idx >> 6;
        unsigned d = (row < N_U) ? deg_u[row] : deg_v[row - N_U];
        float s = d ? (1.f / (float)d) : 0.f;
        float v = outp[idx] * s;
        outp[idx] = v > 0.f ? v : 0.f;
    }
}

extern "C" void kernel_launch(void* const* d_in, const int* in_sizes, int n_in,
                              void* d_out, int out_size, void* d_ws, size_t ws_size,
                              hipStream_t stream)
{
    const int*   adj = (const int*)d_in[0];
    const float* uf  = (const float*)d_in[1];
    const float* vf  = (const float*)d_in[2];
    const float* wu  = (const float*)d_in[3];
    const float* wv  = (const float*)d_in[4];
    float* outp = (float*)d_out;

    unsigned char* ws = (unsigned char*)d_ws;
    const size_t P_BYTES = (size_t)NR * (N_V / 32) * 4 * 64 * 8 * 2;  // 5,242,880
    unsigned short* p_u   = (unsigned short*)ws;
    unsigned short* p_v   = (unsigned short*)(ws + P_BYTES);
    unsigned int*   deg_u = (unsigned int*)(ws + 2 * P_BYTES);
    unsigned int*   deg_v = (unsigned int*)(ws + 2 * P_BYTES + N_U * sizeof(unsigned int));

    hipMemsetAsync(d_out, 0, (size_t)2 * N_U * DIM * sizeof(float), stream);
    hipMemsetAsync(ws + 2 * P_BYTES, 0, (N_U + N_V) * sizeof(unsigned int), stream);

    precompute_P<<<640, 256, 0, stream>>>(uf, vf, wu, wv, p_u, p_v);

    dim3 grid(N_U / BM, 16);
    gemm_masked<0><<<grid, 512, 0, stream>>>(adj, p_u, outp, deg_u);
    gemm_masked<1><<<grid, 512, 0, stream>>>(adj, p_v, outp + (size_t)N_U * DIM, deg_v);

    finalize_k<<<2048, 256, 0, stream>>>(outp, deg_u, deg_v);
}

// Round 3
// 286.016 us; speedup vs baseline: 1.5900x; 1.5900x over previous
//
#include <hip/hip_runtime.h>

#define N_U 8192
#define N_V 8192
#define DIM 64
#define NR 5
#define BM 256      // M rows per block
#define BK 512      // K window per block = 16 ktiles of 32
#define NSTEP 16

typedef __attribute__((ext_vector_type(8))) short short8;
typedef __attribute__((ext_vector_type(4))) float f32x4;

__device__ inline unsigned short f2bf(float x) {
    unsigned u = __float_as_uint(x);
    return (unsigned short)((u + 0x7FFFu + ((u >> 16) & 1u)) >> 16);
}

// P fragment linear index (shorts) for (r, k, o).
// Bijection within a ktile: lane-group g = (k>>3)&3, j = k&7  (k = g*8+j).
// Same map is used for the A-mask build, so the permutation cancels in MFMA.
__device__ inline size_t pfrag_idx(int r, int k, int o) {
    int ktile = k >> 5;
    int g     = (k >> 3) & 3;
    int j     = k & 7;
    int lane  = g * 16 + (o & 15);
    int n     = o >> 4;
    return ((((size_t)r * (N_V / 32) + ktile) * 4 + n) * 64 + lane) * 8 + j;
}

// ---------------- P precompute: P[r][v][o] = sum_f feat[v][f] * W[r][f][o] ----
__global__ __launch_bounds__(256) void precompute_P(
    const float* __restrict__ u_feat, const float* __restrict__ v_feat,
    const float* __restrict__ w_u, const float* __restrict__ w_v,
    unsigned short* __restrict__ p_u, unsigned short* __restrict__ p_v)
{
    int wid  = (blockIdx.x * blockDim.x + threadIdx.x) >> 6;
    int lane = threadIdx.x & 63;
    const int tasks = 2 * NR * (N_V / 32);
    if (wid >= tasks) return;
    int dir  = wid / (NR * (N_V / 32));
    int rem  = wid % (NR * (N_V / 32));
    int r    = rem / (N_V / 32);
    int v0   = (rem % (N_V / 32)) * 32;

    const float* feat = dir ? u_feat : v_feat;
    const float* w    = dir ? w_v : w_u;
    unsigned short* dst = dir ? p_v : p_u;

    float wreg[DIM];
#pragma unroll
    for (int f = 0; f < DIM; ++f) wreg[f] = w[(r * DIM + f) * DIM + lane];

    for (int v = v0; v < v0 + 32; ++v) {
        float x = feat[(size_t)v * DIM + lane];
        float acc = 0.f;
#pragma unroll
        for (int f = 0; f < DIM; ++f) acc += __shfl(x, f) * wreg[f];
        dst[pfrag_idx(r, v, lane)] = f2bf(acc);
    }
}

// ---------------- masked GEMM: whole adj tile resident in LDS as nibbles ----
// out[row][o] += sum_r sum_k (adj==r+1)[row][k] * P[r][k][o]
// TRANS=0: row=u, k=v (2KB-contiguous row reads). TRANS=1: row=v, k=u (4x4 transpose).
// 512 thr = 8 waves; wave owns 32 rows (2 m-tiles) x all 4 n-slices.
// LDS nibble tile [256][256B], XOR swizzle d^=(row&31). No barriers in main loop.
template <int TRANS>
__global__ __launch_bounds__(512, 4) void gemm_masked(
    const int* __restrict__ adj, const unsigned short* __restrict__ pfrag,
    float* __restrict__ outp, unsigned int* __restrict__ deg)
{
    __shared__ unsigned char tile[BM][256];   // 64 KB
    __shared__ unsigned int  cnt[BM];

    const int tid  = threadIdx.x;
    const int lane = tid & 63;
    const int wv   = tid >> 6;
    const int b0   = blockIdx.x * BM;
    const int k0   = blockIdx.y * BK;

    unsigned cpack = 0;   // TRANS=1 per-thread packed byte counters

    // ================= staging =================
    if (TRANS == 0) {
        int4 pre[4], nxt[4];
        const int sub = tid & 31;            // 32 threads per row
        auto issue = [&](int rnd, int4* dst) {
            int row = rnd * 16 + (tid >> 5);
            const int* base = adj + (size_t)(b0 + row) * N_V + k0 + sub * 4;
#pragma unroll
            for (int it = 0; it < 4; ++it) dst[it] = *(const int4*)(base + it * 128);
        };
        issue(0, pre);
        for (int rnd = 0; rnd < 16; ++rnd) {
            if (rnd + 1 < 16) issue(rnd + 1, nxt);
            int row = rnd * 16 + (tid >> 5);
            unsigned lo = 0, hi = 0;
#pragma unroll
            for (int it = 0; it < 4; ++it) {
                int4 a = pre[it];
                unsigned long long bx = __ballot(a.x != 0), by = __ballot(a.y != 0);
                unsigned long long bz = __ballot(a.z != 0), bw = __ballot(a.w != 0);
                lo += __popcll(bx & 0xFFFFFFFFull) + __popcll(by & 0xFFFFFFFFull) +
                      __popcll(bz & 0xFFFFFFFFull) + __popcll(bw & 0xFFFFFFFFull);
                hi += __popcll(bx >> 32) + __popcll(by >> 32) +
                      __popcll(bz >> 32) + __popcll(bw >> 32);
                unsigned pk = (unsigned)a.x | ((unsigned)a.y << 4) |
                              ((unsigned)a.z << 8) | ((unsigned)a.w << 12);
                int d  = it * 16 + (sub >> 1);
                int dp = d ^ (row & 31);
                *(unsigned short*)&tile[row][dp * 4 + (sub & 1) * 2] = (unsigned short)pk;
            }
            if ((tid & 31) == 0) cnt[row] = (lane & 32) ? hi : lo;
#pragma unroll
            for (int it = 0; it < 4; ++it) pre[it] = nxt[it];
        }
    } else {
        const int v4 = (tid & 63) * 4;
        int4 pre[4], nxt[4];
        auto issue = [&](int rnd, int4* dst) {
            int u0 = rnd * 32 + (tid >> 6) * 4;
#pragma unroll
            for (int c = 0; c < 4; ++c)
                dst[c] = *(const int4*)(adj + (size_t)(k0 + u0 + c) * N_V + b0 + v4);
        };
        issue(0, pre);
        for (int rnd = 0; rnd < 16; ++rnd) {
            if (rnd + 1 < 16) issue(rnd + 1, nxt);
            const int* q0 = (const int*)&pre[0]; const int* q1 = (const int*)&pre[1];
            const int* q2 = (const int*)&pre[2]; const int* q3 = (const int*)&pre[3];
            int d    = rnd * 4 + ((tid >> 6) >> 1);
            int half = (tid >> 6) & 1;
#pragma unroll
            for (int cc = 0; cc < 4; ++cc) {
                int x0 = q0[cc], x1 = q1[cc], x2 = q2[cc], x3 = q3[cc];
                unsigned pk = (unsigned)x0 | ((unsigned)x1 << 4) |
                              ((unsigned)x2 << 8) | ((unsigned)x3 << 12);
                int row = v4 + cc;
                int dp  = d ^ (row & 31);
                *(unsigned short*)&tile[row][dp * 4 + half * 2] = (unsigned short)pk;
                cpack += (unsigned)((x0 != 0) + (x1 != 0) + (x2 != 0) + (x3 != 0)) << (8 * cc);
            }
#pragma unroll
            for (int c = 0; c < 4; ++c) pre[c] = nxt[c];
        }
    }
    __syncthreads();

    // ================= main loop: no barriers =================
    f32x4 acc[2][4];
#pragma unroll
    for (int m = 0; m < 2; ++m)
#pragma unroll
        for (int n = 0; n < 4; ++n) acc[m][n] = (f32x4){0.f, 0.f, 0.f, 0.f};

    const int mrow = wv * 32;
    for (int s = 0; s < NSTEP; ++s) {
        unsigned nib[2];
#pragma unroll
        for (int m = 0; m < 2; ++m) {
            int row = mrow + m * 16 + (lane & 15);
            int d   = s * 4 + (lane >> 4);
            nib[m] = *(const unsigned*)&tile[row][((d ^ (row & 31)) << 2)];
        }
        const int ktg = (k0 >> 5) + s;
#pragma unroll
        for (int r = 0; r < NR; ++r) {
            short8 bf[4];
#pragma unroll
            for (int n = 0; n < 4; ++n)
                bf[n] = *(const short8*)(pfrag +
                         ((((size_t)r * (N_V / 32) + ktg) * 4 + n) * 64 + lane) * 8);
            short8 am[2];
#pragma unroll
            for (int m = 0; m < 2; ++m)
#pragma unroll
                for (int j = 0; j < 8; ++j) {
                    unsigned nb = (nib[m] >> (4 * j)) & 0xFu;
                    am[m][j] = (short)(nb == (unsigned)(r + 1) ? 0x3F80 : 0);
                }
#pragma unroll
            for (int n = 0; n < 4; ++n) {
                acc[0][n] = __builtin_amdgcn_mfma_f32_16x16x32_bf16(am[0], bf[n], acc[0][n], 0, 0, 0);
                acc[1][n] = __builtin_amdgcn_mfma_f32_16x16x32_bf16(am[1], bf[n], acc[1][n], 0, 0, 0);
            }
        }
    }

    // ================= epilogue =================
    // C layout: col = lane&15, row = (lane>>4)*4 + q
#pragma unroll
    for (int m = 0; m < 2; ++m) {
        int rbase = b0 + mrow + m * 16 + ((lane >> 4) << 2);
#pragma unroll
        for (int n = 0; n < 4; ++n)
#pragma unroll
            for (int q = 0; q < 4; ++q)
                atomicAdd(&outp[(size_t)(rbase + q) * DIM + n * 16 + (lane & 15)], acc[m][n][q]);
    }

    if (TRANS == 0) {
        if (tid < BM) atomicAdd(&deg[b0 + tid], cnt[tid]);
    } else {
        __syncthreads();
        unsigned* sc = (unsigned*)&tile[0][0];
        sc[tid] = cpack;
        __syncthreads();
        if (tid < BM) {
            unsigned tot = 0;
            int base = tid >> 2, byte = tid & 3;
#pragma unroll
            for (int j = 0; j < 8; ++j) tot += (sc[j * 64 + base] >> (8 * byte)) & 0xFFu;
            atomicAdd(&deg[b0 + tid], tot);
        }
    }
}

// ---------------- finalize: scale by 1/deg, ReLU ----------------
__global__ __launch_bounds__(256) void finalize_k(
    float* __restrict__ outp, const unsigned int* __restrict__ deg_u,
    const unsigned int* __restrict__ deg_v)
{
    int idx = blockIdx.x * blockDim.x + threadIdx.x;
    const int total = 2 * N_U * DIM;
    for (; idx < total; idx += gridDim.x * blockDim.x) {
        int row = idx >> 6;
        unsigned d = (row < N_U) ? deg_u[row] : deg_v[row - N_U];
        float s = d ? (1.f / (float)d) : 0.f;
        float v = outp[idx] * s;
        outp[idx] = v > 0.f ? v : 0.f;
    }
}

extern "C" void kernel_launch(void* const* d_in, const int* in_sizes, int n_in,
                              void* d_out, int out_size, void* d_ws, size_t ws_size,
                              hipStream_t stream)
{
    const int*   adj = (const int*)d_in[0];
    const float* uf  = (const float*)d_in[1];
    const float* vf  = (const float*)d_in[2];
    const float* wu  = (const float*)d_in[3];
    const float* wv  = (const float*)d_in[4];
    float* outp = (float*)d_out;

    unsigned char* ws = (unsigned char*)d_ws;
    const size_t P_BYTES = (size_t)NR * (N_V / 32) * 4 * 64 * 8 * 2;  // 5,242,880
    unsigned short* p_u   = (unsigned short*)ws;
    unsigned short* p_v   = (unsigned short*)(ws + P_BYTES);
    unsigned int*   deg_u = (unsigned int*)(ws + 2 * P_BYTES);
    unsigned int*   deg_v = (unsigned int*)(ws + 2 * P_BYTES + N_U * sizeof(unsigned int));

    hipMemsetAsync(d_out, 0, (size_t)2 * N_U * DIM * sizeof(float), stream);
    hipMemsetAsync(ws + 2 * P_BYTES, 0, (N_U + N_V) * sizeof(unsigned int), stream);

    precompute_P<<<640, 256, 0, stream>>>(uf, vf, wu, wv, p_u, p_v);

    dim3 grid(N_U / BM, N_V / BK);
    gemm_masked<0><<<grid, 512, 0, stream>>>(adj, p_u, outp, deg_u);
    gemm_masked<1><<<grid, 512, 0, stream>>>(adj, p_v, outp + (size_t)N_U * DIM, deg_v);

    finalize_k<<<2048, 256, 0, stream>>>(outp, deg_u, deg_v);
}

// Round 4
// 270.499 us; speedup vs baseline: 1.6813x; 1.0574x over previous
//
#include <hip/hip_runtime.h>

#define N_U 8192
#define N_V 8192
#define DIM 64
#define NR 5
#define BM 256      // u rows per block
#define BK 512      // v cols per block (16 ktiles of 32)

typedef __attribute__((ext_vector_type(8))) short short8;
typedef __attribute__((ext_vector_type(4))) float f32x4;

__device__ inline unsigned short f2bf(float x) {
    unsigned u = __float_as_uint(x);
    return (unsigned short)((u + 0x7FFFu + ((u >> 16) & 1u)) >> 16);
}

// P fragment linear index (shorts) for (r, k, o).
// Bijection within a ktile: g = (k>>3)&3, j = k&7. Same map used for the
// A-mask build, so the permutation cancels inside the MFMA.
__device__ inline size_t pfrag_idx(int r, int k, int o) {
    int ktile = k >> 5;
    int g     = (k >> 3) & 3;
    int j     = k & 7;
    int lane  = g * 16 + (o & 15);
    int n     = o >> 4;
    return ((((size_t)r * (N_V / 32) + ktile) * 4 + n) * 64 + lane) * 8 + j;
}

// ---------------- zero-init (replaces pathological rocclr fill) ----------------
__global__ __launch_bounds__(256) void zero_k(float* __restrict__ outp,
                                              unsigned* __restrict__ deg)
{
    const int stride = gridDim.x * blockDim.x;
    int i = blockIdx.x * blockDim.x + threadIdx.x;
    int4 z = {0, 0, 0, 0};
    for (int idx = i; idx < 2 * N_U * DIM / 4; idx += stride) ((int4*)outp)[idx] = z;
    for (int idx = i; idx < (N_U + N_V) / 4; idx += stride) ((int4*)deg)[idx] = z;
}

// ---------------- P precompute: P[r][v][o] = sum_f feat[v][f] * W[r][f][o] ----
__global__ __launch_bounds__(256) void precompute_P(
    const float* __restrict__ u_feat, const float* __restrict__ v_feat,
    const float* __restrict__ w_u, const float* __restrict__ w_v,
    unsigned short* __restrict__ p_u, unsigned short* __restrict__ p_v)
{
    int wid  = (blockIdx.x * blockDim.x + threadIdx.x) >> 6;
    int lane = threadIdx.x & 63;
    const int tasks = 2 * NR * (N_V / 32);
    if (wid >= tasks) return;
    int dir  = wid / (NR * (N_V / 32));
    int rem  = wid % (NR * (N_V / 32));
    int r    = rem / (N_V / 32);
    int v0   = (rem % (N_V / 32)) * 32;

    const float* feat = dir ? u_feat : v_feat;
    const float* w    = dir ? w_v : w_u;
    unsigned short* dst = dir ? p_v : p_u;

    float wreg[DIM];
#pragma unroll
    for (int f = 0; f < DIM; ++f) wreg[f] = w[(r * DIM + f) * DIM + lane];

    for (int v = v0; v < v0 + 32; ++v) {
        float x = feat[(size_t)v * DIM + lane];
        float acc = 0.f;
#pragma unroll
        for (int f = 0; f < DIM; ++f) acc += __shfl(x, f) * wreg[f];
        dst[pfrag_idx(r, v, lane)] = f2bf(acc);
    }
}

// ---------------- fused masked GEMM: one adj pass -> both directions ----------
// Nibble tile[row=u_local][nibble col=v_local], swizzled: dword index
// d = (c>>3) ^ (row&31); nibble value at bit 4*(c&7) of that dword.
// u-part: out_u[u][o] += sum_r sum_v mask, k=v  (16 ktiles, rows from tile dwords)
// v-part: out_v[v][o] += sum_r sum_u mask, k=u  (8 ktiles, transposed nibble reads:
//         per (j,m) the wave touches 8 distinct dwords / 8 banks, 8-lane broadcast)
__global__ __launch_bounds__(512, 4) void gemm_fused(
    const int* __restrict__ adj,
    const unsigned short* __restrict__ p_u, const unsigned short* __restrict__ p_v,
    float* __restrict__ outp, unsigned int* __restrict__ deg)
{
    __shared__ unsigned char tile[BM][256];     // 64 KB
    __shared__ unsigned int  cnt_u[BM];         // 1 KB
    __shared__ unsigned int  scv[512][4];       // 8 KB: deg_v packed partials

    const int tid  = threadIdx.x;
    const int lane = tid & 63;
    const int wv   = tid >> 6;
    const int b0   = blockIdx.x * BM;          // u base
    const int k0   = blockIdx.y * BK;          // v base
    float* out_u = outp;
    float* out_v = outp + (size_t)N_U * DIM;
    unsigned* deg_u = deg;
    unsigned* deg_v = deg + N_U;

    // ================= staging (R3-verified pattern + deg_v counters) =========
    {
        int4 pre[4], nxt[4];
        const int sub = tid & 31;               // 32 threads per row
        unsigned cv[4] = {0, 0, 0, 0};          // per-col byte counters (q=0..3)
        auto issue = [&](int rnd, int4* dst) {
            int row = rnd * 16 + (tid >> 5);
            const int* base = adj + (size_t)(b0 + row) * N_V + k0 + sub * 4;
#pragma unroll
            for (int it = 0; it < 4; ++it) dst[it] = *(const int4*)(base + it * 128);
        };
        issue(0, pre);
        for (int rnd = 0; rnd < 16; ++rnd) {
            if (rnd + 1 < 16) issue(rnd + 1, nxt);
            int row = rnd * 16 + (tid >> 5);
            unsigned lo = 0, hi = 0;
#pragma unroll
            for (int it = 0; it < 4; ++it) {
                int4 a = pre[it];
                unsigned long long bx = __ballot(a.x != 0), by = __ballot(a.y != 0);
                unsigned long long bz = __ballot(a.z != 0), bw = __ballot(a.w != 0);
                lo += __popcll(bx & 0xFFFFFFFFull) + __popcll(by & 0xFFFFFFFFull) +
                      __popcll(bz & 0xFFFFFFFFull) + __popcll(bw & 0xFFFFFFFFull);
                hi += __popcll(bx >> 32) + __popcll(by >> 32) +
                      __popcll(bz >> 32) + __popcll(bw >> 32);
                cv[it] += (unsigned)(a.x != 0) | ((unsigned)(a.y != 0) << 8) |
                          ((unsigned)(a.z != 0) << 16) | ((unsigned)(a.w != 0) << 24);
                unsigned pk = (unsigned)a.x | ((unsigned)a.y << 4) |
                              ((unsigned)a.z << 8) | ((unsigned)a.w << 12);
                int d  = it * 16 + (sub >> 1);
                int dp = d ^ (row & 31);
                *(unsigned short*)&tile[row][dp * 4 + (sub & 1) * 2] = (unsigned short)pk;
            }
            if ((tid & 31) == 0) cnt_u[row] = (lane & 32) ? hi : lo;
#pragma unroll
            for (int it = 0; it < 4; ++it) pre[it] = nxt[it];
        }
#pragma unroll
        for (int it = 0; it < 4; ++it) scv[tid][it] = cv[it];
    }
    __syncthreads();

    const unsigned* t32 = (const unsigned*)&tile[0][0];

    // ================= u-part: rows = u (R3-verified), k = v ==================
    {
        f32x4 acc[2][4];
#pragma unroll
        for (int m = 0; m < 2; ++m)
#pragma unroll
            for (int n = 0; n < 4; ++n) acc[m][n] = (f32x4){0.f, 0.f, 0.f, 0.f};

        const int mrow = wv * 32;
        for (int s = 0; s < 16; ++s) {
            unsigned nib[2];
#pragma unroll
            for (int m = 0; m < 2; ++m) {
                int row = mrow + m * 16 + (lane & 15);
                int d   = s * 4 + (lane >> 4);
                nib[m] = t32[row * 64 + (d ^ (row & 31))];
            }
            const int ktg = (k0 >> 5) + s;
#pragma unroll
            for (int r = 0; r < NR; ++r) {
                short8 bf[4];
#pragma unroll
                for (int n = 0; n < 4; ++n)
                    bf[n] = *(const short8*)(p_u +
                             ((((size_t)r * (N_V / 32) + ktg) * 4 + n) * 64 + lane) * 8);
                short8 am[2];
#pragma unroll
                for (int m = 0; m < 2; ++m)
#pragma unroll
                    for (int j = 0; j < 8; ++j)
                        am[m][j] = (short)(((nib[m] >> (4 * j)) & 0xFu) == (unsigned)(r + 1) ? 0x3F80 : 0);
#pragma unroll
                for (int n = 0; n < 4; ++n) {
                    acc[0][n] = __builtin_amdgcn_mfma_f32_16x16x32_bf16(am[0], bf[n], acc[0][n], 0, 0, 0);
                    acc[1][n] = __builtin_amdgcn_mfma_f32_16x16x32_bf16(am[1], bf[n], acc[1][n], 0, 0, 0);
                }
            }
        }
        // epilogue (C: col=lane&15, row=(lane>>4)*4+q) — flush before v-part
#pragma unroll
        for (int m = 0; m < 2; ++m) {
            int rbase = b0 + mrow + m * 16 + ((lane >> 4) << 2);
#pragma unroll
            for (int n = 0; n < 4; ++n)
#pragma unroll
                for (int q = 0; q < 4; ++q)
                    atomicAdd(&out_u[(size_t)(rbase + q) * DIM + n * 16 + (lane & 15)], acc[m][n][q]);
        }
    }

    // ================= v-part: rows = v, k = u (transposed reads) =============
    {
        f32x4 acc[4][4];
#pragma unroll
        for (int m = 0; m < 4; ++m)
#pragma unroll
            for (int n = 0; n < 4; ++n) acc[m][n] = (f32x4){0.f, 0.f, 0.f, 0.f};

        const int g = lane >> 4;
        int cd[4], sh[4];
#pragma unroll
        for (int m = 0; m < 4; ++m) {
            int c = wv * 64 + m * 16 + (lane & 15);   // v_local, lane-const per m
            cd[m] = c >> 3;
            sh[m] = 4 * (c & 7);
        }

        for (int kt = 0; kt < 8; ++kt) {
            unsigned nbp[4] = {0, 0, 0, 0};          // 8 packed nibbles per m
#pragma unroll
            for (int j = 0; j < 8; ++j) {
                int row = kt * 32 + g * 8 + j;
                int rx  = row & 31;                  // = g*8+j
#pragma unroll
                for (int m = 0; m < 4; ++m) {
                    unsigned dw = t32[row * 64 + (cd[m] ^ rx)];
                    nbp[m] |= ((dw >> sh[m]) & 0xFu) << (4 * j);
                }
            }
            const int ktg = (b0 >> 5) + kt;
#pragma unroll
            for (int r = 0; r < NR; ++r) {
                short8 bf[4];
#pragma unroll
                for (int n = 0; n < 4; ++n)
                    bf[n] = *(const short8*)(p_v +
                             ((((size_t)r * (N_U / 32) + ktg) * 4 + n) * 64 + lane) * 8);
#pragma unroll
                for (int m = 0; m < 4; ++m) {
                    short8 am;
#pragma unroll
                    for (int j = 0; j < 8; ++j)
                        am[j] = (short)(((nbp[m] >> (4 * j)) & 0xFu) == (unsigned)(r + 1) ? 0x3F80 : 0);
#pragma unroll
                    for (int n = 0; n < 4; ++n)
                        acc[m][n] = __builtin_amdgcn_mfma_f32_16x16x32_bf16(am, bf[n], acc[m][n], 0, 0, 0);
                }
            }
        }
#pragma unroll
        for (int m = 0; m < 4; ++m) {
            int rbase = k0 + wv * 64 + m * 16 + ((lane >> 4) << 2);
#pragma unroll
            for (int n = 0; n < 4; ++n)
#pragma unroll
                for (int q = 0; q < 4; ++q)
                    atomicAdd(&out_v[(size_t)(rbase + q) * DIM + n * 16 + (lane & 15)], acc[m][n][q]);
        }
    }

    // ================= degree reductions =================
    if (tid < BM) atomicAdd(&deg_u[b0 + tid], cnt_u[tid]);
    {
        int c   = tid;                      // one v-col per thread
        int it  = c >> 7;
        int sub = (c & 127) >> 2;
        int q   = c & 3;
        unsigned tot = 0;
#pragma unroll
        for (int rg = 0; rg < 16; ++rg)
            tot += (scv[rg * 32 + sub][it] >> (8 * q)) & 0xFFu;
        atomicAdd(&deg_v[k0 + c], tot);
    }
}

// ---------------- finalize: scale by 1/deg, ReLU ----------------
__global__ __launch_bounds__(256) void finalize_k(
    float* __restrict__ outp, const unsigned int* __restrict__ deg_u,
    const unsigned int* __restrict__ deg_v)
{
    int idx = blockIdx.x * blockDim.x + threadIdx.x;
    const int total = 2 * N_U * DIM;
    for (; idx < total; idx += gridDim.x * blockDim.x) {
        int row = idx >> 6;
        unsigned d = (row < N_U) ? deg_u[row] : deg_v[row - N_U];
        float s = d ? (1.f / (float)d) : 0.f;
        float v = outp[idx] * s;
        outp[idx] = v > 0.f ? v : 0.f;
    }
}

extern "C" void kernel_launch(void* const* d_in, const int* in_sizes, int n_in,
                              void* d_out, int out_size, void* d_ws, size_t ws_size,
                              hipStream_t stream)
{
    const int*   adj = (const int*)d_in[0];
    const float* uf  = (const float*)d_in[1];
    const float* vf  = (const float*)d_in[2];
    const float* wu  = (const float*)d_in[3];
    const float* wv  = (const float*)d_in[4];
    float* outp = (float*)d_out;

    unsigned char* ws = (unsigned char*)d_ws;
    const size_t P_BYTES = (size_t)NR * (N_V / 32) * 4 * 64 * 8 * 2;  // 5,242,880
    unsigned short* p_u = (unsigned short*)ws;
    unsigned short* p_v = (unsigned short*)(ws + P_BYTES);
    unsigned int*   deg = (unsigned int*)(ws + 2 * P_BYTES);   // deg_u | deg_v

    zero_k<<<1024, 256, 0, stream>>>(outp, deg);
    precompute_P<<<640, 256, 0, stream>>>(uf, vf, wu, wv, p_u, p_v);

    dim3 grid(N_U / BM, N_V / BK);
    gemm_fused<<<grid, 512, 0, stream>>>(adj, p_u, p_v, outp, deg);

    finalize_k<<<2048, 256, 0, stream>>>(outp, deg, deg + N_U);
}